// Round 1
// baseline (432.491 us; speedup 1.0000x reference)
//
#include <hip/hip_runtime.h>

typedef __attribute__((ext_vector_type(8))) short short8;
typedef __attribute__((ext_vector_type(4))) float f32x4;

__device__ __forceinline__ short f2bf(float f) {
    unsigned int u = __builtin_bit_cast(unsigned int, f);
    u += 0x7fffu + ((u >> 16) & 1u);   // round-to-nearest-even
    return (short)(u >> 16);
}

// ---------------------------------------------------------------------------
// Kernel A: partial adjacency sums.  grid (10, 32) = (t-chunk, n), 256 thr.
// At_part[(n*10+tc)*625 + v*25+u] = sum over 30 frames of exp(-2*d2(v,u))
// ---------------------------------------------------------------------------
__global__ void kA(const float* __restrict__ xx, float* __restrict__ At_part) {
    __shared__ float xs3[3][30][25];
    const int tc = blockIdx.x, n = blockIdx.y;
    const int tid = threadIdx.x;
    const float* base = xx + (size_t)n * 22500 + tc * 750;   // xx[n][ch][t][v]
    for (int idx = tid; idx < 2250; idx += 256) {
        int ch = idx / 750, rt = idx % 750;
        xs3[ch][rt / 25][rt % 25] = base[ch * 7500 + rt];
    }
    __syncthreads();
    for (int p = tid; p < 625; p += 256) {
        int v = p / 25, u = p % 25;
        float s = 0.f;
        for (int t = 0; t < 30; ++t) {
            float dx = xs3[0][t][v] - xs3[0][t][u];
            float dy = xs3[1][t][v] - xs3[1][t][u];
            float dz = xs3[2][t][v] - xs3[2][t][u];
            s += __expf(-2.f * (dx * dx + dy * dy + dz * dz));
        }
        At_part[(size_t)(n * 10 + tc) * 625 + p] = s;
    }
}

// ---------------------------------------------------------------------------
// Kernel B: reduce partials -> A_scale (bf16, padded [64][72]),
//           W'' = W * bn_scale (bf16 [192][192]), fused bias (f32 [192]).
// one block, 256 threads.
// ---------------------------------------------------------------------------
__global__ void kB(const float* __restrict__ At_part, const float* __restrict__ A_res,
                   const float* __restrict__ W, const float* __restrict__ b,
                   const float* __restrict__ gamma, const float* __restrict__ beta,
                   const float* __restrict__ rm, const float* __restrict__ rv,
                   short* __restrict__ bsTg, short* __restrict__ Wpg,
                   float* __restrict__ bbg) {
    __shared__ float At[625];
    __shared__ float dinv[25];
    __shared__ float macc[625];
    const int tid = threadIdx.x;
    for (int p = tid; p < 625; p += 256) macc[p] = 0.f;
    __syncthreads();
    for (int n = 0; n < 32; ++n) {
        for (int p = tid; p < 625; p += 256) {
            float s = 0.f;
            for (int tc = 0; tc < 10; ++tc) s += At_part[(size_t)(n * 10 + tc) * 625 + p];
            At[p] = s * (1.f / 300.f);
        }
        __syncthreads();
        if (tid < 25) {
            float d = 0.f;
            for (int u = 0; u < 25; ++u) d += At[tid * 25 + u];
            dinv[tid] = rsqrtf(d);
        }
        __syncthreads();
        for (int p = tid; p < 625; p += 256)
            macc[p] += At[p] * dinv[p / 25] * dinv[p % 25] * (1.f / 32.f);
        __syncthreads();
    }
    // A_scale[col][u] = macc[col%25][u%25] + A_res[col][u], stored padded [64][72]
    for (int idx = tid; idx < 64 * 72; idx += 256) {
        int col = idx / 72, u = idx % 72;
        float v = 0.f;
        if (col < 50 && u < 50) v = macc[(col % 25) * 25 + (u % 25)] + A_res[col * 50 + u];
        bsTg[idx] = f2bf(v);
    }
    for (int idx = tid; idx < 192 * 192; idx += 256) {
        int o = idx / 192;
        float sc = gamma[o] * rsqrtf(rv[o] + 1e-5f);
        Wpg[idx] = f2bf(W[idx] * sc);
    }
    if (tid < 192) {
        float sc = gamma[tid] * rsqrtf(rv[tid] + 1e-5f);
        bbg[tid] = b[tid] * sc + beta[tid] - rm[tid] * sc;
    }
}

// ---------------------------------------------------------------------------
// Kernel C: fused graph-conv + 1x1 conv + BN + ReLU.
// grid (75, 32) = (t-chunk of 4, n), 256 threads = 4 waves.
// GEMM1 per t: agg(96x50) = x_t(96x50) @ A_scale^T     (mfma 16x16x32 bf16)
// GEMM2: out(192x100) = W''(192x192) @ agg2(192x100)   (W'' frags in VGPRs)
// ---------------------------------------------------------------------------
__global__ __launch_bounds__(256, 2)
void kC(const float* __restrict__ x, const short* __restrict__ Wpg,
        const short* __restrict__ bsTg, const float* __restrict__ bbg,
        float* __restrict__ out) {
    __shared__ __align__(16) short xs[96][72];    // x_t bf16, zeros at u=50..63
    __shared__ __align__(16) short bsT[64][72];   // A_scale padded
    __shared__ __align__(16) short a2T[100][200]; // agg2^T: [col=tl*25+vs][c']
    __shared__ float bbs[192];

    const int tid = threadIdx.x;
    const int lane = tid & 63;
    const int wid = tid >> 6;
    const int n = blockIdx.y;
    const int t0 = blockIdx.x * 4;

    // stage A_scale + bias
    {
        const uint4* src = (const uint4*)bsTg;
        uint4* dst = (uint4*)(&bsT[0][0]);
        for (int i = tid; i < (64 * 72 * 2) / 16; i += 256) dst[i] = src[i];
        if (tid < 192) bbs[tid] = bbg[tid];
    }

    // preload W'' fragments: wave w owns output rows [w*48, w*48+48)
    const int r0 = wid * 48 + (lane & 15);
    const int kc = (lane >> 4) * 8;
    short8 wf[3][6];
#pragma unroll
    for (int mt = 0; mt < 3; ++mt)
#pragma unroll
        for (int ks = 0; ks < 6; ++ks)
            wf[mt][ks] = *(const short8*)(Wpg + (r0 + mt * 16) * 192 + ks * 32 + kc);

    __syncthreads();

    // ---- GEMM1 over 4 timesteps ----
    for (int tl = 0; tl < 4; ++tl) {
        const int t = t0 + tl;
        const float* xp = x + ((size_t)n * 96 * 300 + t) * 50;
        for (int idx = tid; idx < 96 * 64; idx += 256) {
            int c = idx >> 6, u = idx & 63;
            float v = (u < 50) ? xp[c * 15000 + u] : 0.f;
            xs[c][u] = f2bf(v);
        }
        __syncthreads();

        f32x4 acc1[6];
        const f32x4 z = {0.f, 0.f, 0.f, 0.f};
#pragma unroll
        for (int mt = 0; mt < 6; ++mt) acc1[mt] = z;
#pragma unroll
        for (int ks = 0; ks < 2; ++ks) {
            short8 bfr = *(const short8*)(&bsT[wid * 16 + (lane & 15)][ks * 32 + kc]);
#pragma unroll
            for (int mt = 0; mt < 6; ++mt) {
                short8 afr = *(const short8*)(&xs[mt * 16 + (lane & 15)][ks * 32 + kc]);
                acc1[mt] = __builtin_amdgcn_mfma_f32_16x16x32_bf16(afr, bfr, acc1[mt], 0, 0, 0);
            }
        }
        const int ncol = wid * 16 + (lane & 15);   // column of agg (0..63, valid <50)
        if (ncol < 50) {
            const int s = ncol / 25, vs = ncol % 25;
            const int arow = tl * 25 + vs;
            const int cb = (lane >> 4) * 4;
#pragma unroll
            for (int mt = 0; mt < 6; ++mt)
#pragma unroll
                for (int r = 0; r < 4; ++r)
                    a2T[arow][s * 96 + mt * 16 + cb + r] = f2bf(acc1[mt][r]);
        }
        __syncthreads();
    }

    // ---- GEMM2 + epilogue ----
    for (int nt = 0; nt < 7; ++nt) {
        const int colr = nt * 16 + (lane & 15);
        const int brow = colr < 100 ? colr : 99;   // clamp pad columns
        const f32x4 z = {0.f, 0.f, 0.f, 0.f};
        f32x4 acc[3];
        acc[0] = z; acc[1] = z; acc[2] = z;
#pragma unroll
        for (int ks = 0; ks < 6; ++ks) {
            short8 bfr = *(const short8*)(&a2T[brow][ks * 32 + kc]);
#pragma unroll
            for (int mt = 0; mt < 3; ++mt)
                acc[mt] = __builtin_amdgcn_mfma_f32_16x16x32_bf16(wf[mt][ks], bfr, acc[mt], 0, 0, 0);
        }
        if (colr < 100) {
            const int tl = colr / 25, vs = colr % 25;
            const int t = t0 + tl;
#pragma unroll
            for (int mt = 0; mt < 3; ++mt) {
                const int ob = wid * 48 + mt * 16 + (lane >> 4) * 4;
                float* op = out + ((size_t)(n * 192 + ob) * 300 + t) * 25 + vs;
#pragma unroll
                for (int r = 0; r < 4; ++r) {
                    float v = acc[mt][r] + bbs[ob + r];
                    op[(size_t)r * 7500] = v > 0.f ? v : 0.f;
                }
            }
        }
    }
}

// ---------------------------------------------------------------------------
extern "C" void kernel_launch(void* const* d_in, const int* in_sizes, int n_in,
                              void* d_out, int out_size, void* d_ws, size_t ws_size,
                              hipStream_t stream) {
    const float* x     = (const float*)d_in[0];
    const float* xx    = (const float*)d_in[1];
    const float* A_res = (const float*)d_in[2];
    const float* W     = (const float*)d_in[3];
    const float* b     = (const float*)d_in[4];
    const float* gamma = (const float*)d_in[5];
    const float* beta  = (const float*)d_in[6];
    const float* rm    = (const float*)d_in[7];
    const float* rv    = (const float*)d_in[8];
    float* out = (float*)d_out;

    char* ws = (char*)d_ws;
    float* At_part = (float*)ws;                    // 320*625*4 = 800000 B
    short* bsTg    = (short*)(ws + 800000);         // 64*72*2   =   9216 B
    short* Wpg     = (short*)(ws + 809216);         // 192*192*2 =  73728 B
    float* bbg     = (float*)(ws + 882944);         // 192*4     =    768 B

    kA<<<dim3(10, 32), 256, 0, stream>>>(xx, At_part);
    kB<<<1, 256, 0, stream>>>(At_part, A_res, W, b, gamma, beta, rm, rv, bsTg, Wpg, bbg);
    kC<<<dim3(75, 32), 256, 0, stream>>>(x, Wpg, bsTg, bbg, out);
}

// Round 2
// 234.757 us; speedup vs baseline: 1.8423x; 1.8423x over previous
//
#include <hip/hip_runtime.h>

typedef __attribute__((ext_vector_type(8))) short short8;
typedef __attribute__((ext_vector_type(4))) short short4v;
typedef __attribute__((ext_vector_type(4))) float f32x4;

__device__ __forceinline__ unsigned short f2bf(float f) {
    unsigned int u = __builtin_bit_cast(unsigned int, f);
    u += 0x7fffu + ((u >> 16) & 1u);   // round-to-nearest-even
    return (unsigned short)(u >> 16);
}
__device__ __forceinline__ unsigned int pack2(float a, float b) {
    return (unsigned int)f2bf(a) | ((unsigned int)f2bf(b) << 16);
}

// ---------------------------------------------------------------------------
// Kernel A: full normalized adjacency contribution per sample.
// grid 32, 256 thr.  Acontrib[n][625] = A_norm(n)/32
// ---------------------------------------------------------------------------
__global__ void kA(const float* __restrict__ xx, float* __restrict__ Acontrib) {
    __shared__ float xs3[3][30][25];
    __shared__ float At[625];
    __shared__ float dinv[25];
    const int n = blockIdx.x, tid = threadIdx.x;
    for (int p = tid; p < 625; p += 256) At[p] = 0.f;
    const float* base = xx + (size_t)n * 22500;
    for (int tc = 0; tc < 10; ++tc) {
        __syncthreads();
        for (int idx = tid; idx < 2250; idx += 256) {
            int ch = idx / 750, rt = idx % 750;
            xs3[ch][rt / 25][rt % 25] = base[ch * 7500 + tc * 750 + rt];
        }
        __syncthreads();
        for (int p = tid; p < 625; p += 256) {
            int v = p / 25, u = p % 25;
            float s = 0.f;
            for (int t = 0; t < 30; ++t) {
                float dx = xs3[0][t][v] - xs3[0][t][u];
                float dy = xs3[1][t][v] - xs3[1][t][u];
                float dz = xs3[2][t][v] - xs3[2][t][u];
                s += __expf(-2.f * (dx * dx + dy * dy + dz * dz));
            }
            At[p] += s;
        }
    }
    __syncthreads();
    if (tid < 25) {
        float d = 0.f;
        for (int u = 0; u < 25; ++u) d += At[tid * 25 + u];
        dinv[tid] = rsqrtf(d * (1.f / 300.f));
    }
    __syncthreads();
    for (int p = tid; p < 625; p += 256)
        Acontrib[n * 625 + p] = At[p] * (1.f / 300.f) * dinv[p / 25] * dinv[p % 25] * (1.f / 32.f);
}

// ---------------------------------------------------------------------------
// Kernel B: block 0 -> bsTg (bf16 [64][72], zero-padded) + fused bias;
//           blocks 1..36 -> W'' = W * bn_scale (bf16, float4-vectorized).
// ---------------------------------------------------------------------------
__global__ void kB(const float* __restrict__ Acontrib, const float* __restrict__ A_res,
                   const float* __restrict__ W, const float* __restrict__ b,
                   const float* __restrict__ gamma, const float* __restrict__ beta,
                   const float* __restrict__ rm, const float* __restrict__ rv,
                   short* __restrict__ bsTg, short* __restrict__ Wpg,
                   float* __restrict__ bbg) {
    const int tid = threadIdx.x;
    if (blockIdx.x == 0) {
        __shared__ float macc[625];
        for (int p = tid; p < 625; p += 256) {
            float s = 0.f;
            for (int n = 0; n < 32; ++n) s += Acontrib[n * 625 + p];
            macc[p] = s;
        }
        __syncthreads();
        for (int idx = tid; idx < 64 * 72; idx += 256) {
            int col = idx / 72, u = idx % 72;
            float v = 0.f;
            if (col < 50 && u < 50) v = macc[(col % 25) * 25 + (u % 25)] + A_res[col * 50 + u];
            bsTg[idx] = (short)f2bf(v);
        }
        if (tid < 192) {
            float sc = gamma[tid] * rsqrtf(rv[tid] + 1e-5f);
            bbg[tid] = b[tid] * sc + beta[tid] - rm[tid] * sc;
        }
    } else {
        const int e = (blockIdx.x - 1) * 1024 + tid * 4;   // 36*1024 = 36864 exact
        const int o = e / 192;
        const float sc = gamma[o] * rsqrtf(rv[o] + 1e-5f);
        float4 w = *(const float4*)(W + e);
        short4v s4 = { (short)f2bf(w.x * sc), (short)f2bf(w.y * sc),
                       (short)f2bf(w.z * sc), (short)f2bf(w.w * sc) };
        *(short4v*)(Wpg + e) = s4;
    }
}

// ---------------------------------------------------------------------------
// Kernel C: fused graph-conv + 1x1 conv + BN + ReLU.
// grid (75, 32), 256 thr = 4 waves.  t-chunk = 4 (200 contiguous floats/row).
// xs: [tl][c][u64] bf16, XOR-swizzled (byte ^= (c&7)<<4), staged once.
// per tl: GEMM1 (B-frags in regs) -> a2T[25][200] -> GEMM2 (W'' frags in regs).
// ---------------------------------------------------------------------------
__global__ __launch_bounds__(256, 2)
void kC(const float* __restrict__ x, const short* __restrict__ Wpg,
        const short* __restrict__ bsTg, const float* __restrict__ bbg,
        float* __restrict__ out) {
    __shared__ __align__(16) char xsb[4 * 96 * 128];   // 49152 B
    __shared__ __align__(16) short a2T[25][200];       // 10000 B

    const int tid = threadIdx.x;
    const int lane = tid & 63;
    const int wid = tid >> 6;
    const int lam = lane & 15;
    const int kc = (lane >> 4) * 8;    // K-offset within fragment (elems)
    const int cb = (lane >> 4) * 4;    // C/D row sub-block
    const int n = blockIdx.y;
    const int t0 = blockIdx.x * 4;

    // W'' fragments in registers: wave owns output rows [wid*48, wid*48+48)
    const int r0 = wid * 48 + lam;
    short8 wf[3][6];
#pragma unroll
    for (int mt = 0; mt < 3; ++mt)
#pragma unroll
        for (int ks = 0; ks < 6; ++ks)
            wf[mt][ks] = *(const short8*)(Wpg + (r0 + mt * 16) * 192 + ks * 32 + kc);

    // A_scale (GEMM1 B) fragments in registers
    const int ncol = wid * 16 + lam;                   // output col 0..63 (valid<50)
    const short8 bq0 = *(const short8*)(bsTg + ncol * 72 + kc);
    const short8 bq1 = *(const short8*)(bsTg + ncol * 72 + 32 + kc);

    // fused bias in registers
    float bbv[3][4];
#pragma unroll
    for (int mt = 0; mt < 3; ++mt)
#pragma unroll
        for (int r = 0; r < 4; ++r)
            bbv[mt][r] = bbg[wid * 48 + mt * 16 + cb + r];

    // ---- stage x: 96 rows x 200 contiguous floats, float4 loads ----
    const float* xbase = x + (size_t)n * 1440000 + (size_t)t0 * 50;
    for (int idx = tid; idx < 4800; idx += 256) {
        int c = idx / 50, q = idx - c * 50;
        float4 v = *(const float4*)(xbase + (size_t)c * 15000 + 4 * q);
        int g = 4 * q;                      // 0..196; pairs never straddle tl (50 even)
        int tl0 = g / 50,       u0 = g - 50 * tl0;
        int tl1 = (g + 2) / 50, u1 = (g + 2) - 50 * tl1;
        int swz = (c & 7) << 4;
        *(unsigned int*)(xsb + ((tl0 * 12288 + c * 128 + u0 * 2) ^ swz)) = pack2(v.x, v.y);
        *(unsigned int*)(xsb + ((tl1 * 12288 + c * 128 + u1 * 2) ^ swz)) = pack2(v.z, v.w);
    }
    // zero the u=50..63 pad (finite: pad * A_scale-zero must be 0, not NaN)
    for (int idx = tid; idx < 2688; idx += 256) {
        int r = idx / 7, k = idx - r * 7;
        int tl = r / 96, c = r - 96 * tl;
        int u = 50 + 2 * k;
        *(unsigned int*)(xsb + ((tl * 12288 + c * 128 + u * 2) ^ ((c & 7) << 4))) = 0;
    }
    __syncthreads();

    const f32x4 z = {0.f, 0.f, 0.f, 0.f};

#pragma unroll 1
    for (int tl = 0; tl < 4; ++tl) {
        // ---- GEMM1: agg(96x50) for timestep t0+tl ----
        f32x4 acc1[6];
#pragma unroll
        for (int mt = 0; mt < 6; ++mt) acc1[mt] = z;
#pragma unroll
        for (int ks = 0; ks < 2; ++ks) {
#pragma unroll
            for (int mt = 0; mt < 6; ++mt) {
                int c = mt * 16 + lam;
                const short8 afr = *(const short8*)(xsb +
                    ((tl * 12288 + c * 128 + (ks * 32 + kc) * 2) ^ ((c & 7) << 4)));
                acc1[mt] = __builtin_amdgcn_mfma_f32_16x16x32_bf16(
                    afr, ks ? bq1 : bq0, acc1[mt], 0, 0, 0);
            }
        }
        if (ncol < 50) {
            const int s = ncol >= 25 ? 1 : 0;
            const int vs = ncol - 25 * s;
#pragma unroll
            for (int mt = 0; mt < 6; ++mt) {
                short4v w = { (short)f2bf(acc1[mt][0]), (short)f2bf(acc1[mt][1]),
                              (short)f2bf(acc1[mt][2]), (short)f2bf(acc1[mt][3]) };
                *(short4v*)(&a2T[vs][s * 96 + mt * 16 + cb]) = w;
            }
        }
        __syncthreads();

        // ---- GEMM2: out(192x25) for this timestep ----
        f32x4 acc[3][2];
#pragma unroll
        for (int mt = 0; mt < 3; ++mt) { acc[mt][0] = z; acc[mt][1] = z; }
        const int c1 = (16 + lam) < 25 ? (16 + lam) : 24;   // clamp pad cols
#pragma unroll
        for (int ks = 0; ks < 6; ++ks) {
            const short8 b0 = *(const short8*)(&a2T[lam][ks * 32 + kc]);
            const short8 b1 = *(const short8*)(&a2T[c1][ks * 32 + kc]);
#pragma unroll
            for (int mt = 0; mt < 3; ++mt) {
                acc[mt][0] = __builtin_amdgcn_mfma_f32_16x16x32_bf16(wf[mt][ks], b0, acc[mt][0], 0, 0, 0);
                acc[mt][1] = __builtin_amdgcn_mfma_f32_16x16x32_bf16(wf[mt][ks], b1, acc[mt][1], 0, 0, 0);
            }
        }
        const int t = t0 + tl;
#pragma unroll
        for (int nt = 0; nt < 2; ++nt) {
            const int col = nt * 16 + lam;
            if (col < 25) {
#pragma unroll
                for (int mt = 0; mt < 3; ++mt) {
                    const int ob = wid * 48 + mt * 16 + cb;
                    float* op = out + ((size_t)(n * 192 + ob) * 300 + t) * 25 + col;
#pragma unroll
                    for (int r = 0; r < 4; ++r) {
                        float v = acc[mt][nt][r] + bbv[mt][r];
                        op[(size_t)r * 7500] = v > 0.f ? v : 0.f;
                    }
                }
            }
        }
        if (tl < 3) __syncthreads();   // WAR on a2T before next GEMM1 write
    }
}

// ---------------------------------------------------------------------------
extern "C" void kernel_launch(void* const* d_in, const int* in_sizes, int n_in,
                              void* d_out, int out_size, void* d_ws, size_t ws_size,
                              hipStream_t stream) {
    const float* x     = (const float*)d_in[0];
    const float* xx    = (const float*)d_in[1];
    const float* A_res = (const float*)d_in[2];
    const float* W     = (const float*)d_in[3];
    const float* b     = (const float*)d_in[4];
    const float* gamma = (const float*)d_in[5];
    const float* beta  = (const float*)d_in[6];
    const float* rm    = (const float*)d_in[7];
    const float* rv    = (const float*)d_in[8];
    float* out = (float*)d_out;

    char* ws = (char*)d_ws;
    float* Acontrib = (float*)ws;                   // 32*625*4 = 80000 B
    short* bsTg     = (short*)(ws + 80000);         // 64*72*2  =  9216 B
    short* Wpg      = (short*)(ws + 89216);         // 192*192*2= 73728 B
    float* bbg      = (float*)(ws + 162944);        // 192*4    =   768 B

    kA<<<32, 256, 0, stream>>>(xx, Acontrib);
    kB<<<37, 256, 0, stream>>>(Acontrib, A_res, W, b, gamma, beta, rm, rv, bsTg, Wpg, bbg);
    kC<<<dim3(75, 32), 256, 0, stream>>>(x, Wpg, bsTg, bbg, out);
}